// Round 3
// baseline (6092.387 us; speedup 1.0000x reference)
//
#include <hip/hip_runtime.h>

// ============================================================================
// Dilated GRU encoder-decoder, persistent-kernel design for MI355X. Round 3.
//
// Fixes over round 2 (error was structural, not numeric):
//  1. DOUBLE-BUFFERED h exchange (parity ping-pong) — round 1/2 had a
//     write-after-read race: a fast group member could overwrite h(t) while a
//     slow member was still reading it.
//  2. All cross-workgroup h traffic is relaxed AGENT-scope atomics on packed
//     u32 {bf16 hi | bf16 lo}; counter uses release/acquire — correct under
//     any WG->XCD mapping.
//  3. ws_size-adaptive: staged split-bf16 X planes if ws is big enough,
//     otherwise direct strided fp32 reads of X0/X1 (no OOB possible).
//     Counters + h buffer live at offset 0 (tiny, always fit).
//  4. Weights are loaded fp32 -> split hi/lo bf16 in registers at kernel
//     start (prep_w kernel removed).
// Precision: 3-term Markidis split everywhere (residual ~2^-16/step).
// ============================================================================

typedef __bf16 bf16x8 __attribute__((ext_vector_type(8)));
typedef float  f32x4  __attribute__((ext_vector_type(4)));

#define MFMA16(a, b, c) __builtin_amdgcn_mfma_f32_16x16x32_bf16(a, b, c, 0, 0, 0)

// ---- workspace byte offsets (small, mandatory stuff first) ----------------
#define OFF_CNT   0ULL          // 8 groups * 64 B
#define OFF_HB    4096ULL       // 2 * 128 * 512 * 4 B (packed u32, dbuf)
#define OFF_XX0H  528384ULL     // 256*128*1024 bf16 = 67108864 B
#define OFF_XX0L  67637248ULL
#define OFF_XX1H  134746112ULL  // 48*128*512 bf16 = 6291456 B
#define OFF_XX1L  141037568ULL
#define NEED_FULL 147329024ULL  // staged path requires this many ws bytes

static __device__ __forceinline__ void split_bf(float x, unsigned short& hi,
                                                unsigned short& lo) {
  union { __bf16 b; unsigned short u; } c;
  c.b = (__bf16)x; hi = c.u;
  float fh = (float)c.b;
  c.b = (__bf16)(x - fh); lo = c.u;
}
static __device__ __forceinline__ void split8(const float* __restrict__ p,
                                              bf16x8& h, bf16x8& l) {
#pragma unroll
  for (int j = 0; j < 8; ++j) {
    const float x = p[j];
    const __bf16 hb = (__bf16)x;
    h[j] = hb;
    l[j] = (__bf16)(x - (float)hb);
  }
}
static __device__ __forceinline__ void split8a(const float* xv, bf16x8& h, bf16x8& l) {
#pragma unroll
  for (int j = 0; j < 8; ++j) {
    const float x = xv[j];
    const __bf16 hb = (__bf16)x;
    h[j] = hb;
    l[j] = (__bf16)(x - (float)hb);
  }
}
static __device__ __forceinline__ void load_h_frag(const unsigned int* __restrict__ p,
                                                   bf16x8& h, bf16x8& l) {
  unsigned int w[8];
#pragma unroll
  for (int j = 0; j < 8; ++j)
    w[j] = __hip_atomic_load(p + j, __ATOMIC_RELAXED, __HIP_MEMORY_SCOPE_AGENT);
  union { unsigned short u; __bf16 b; } c;
#pragma unroll
  for (int j = 0; j < 8; ++j) {
    c.u = (unsigned short)(w[j] & 0xffffu); h[j] = c.b;
    c.u = (unsigned short)(w[j] >> 16);     l[j] = c.b;
  }
}
static __device__ __forceinline__ float sigmoidf_(float x) {
  return 1.0f / (1.0f + __expf(-x));
}
static __device__ __forceinline__ float tanhf_(float x) {
  x = fminf(fmaxf(x, -15.0f), 15.0f);
  float e = __expf(2.0f * x);
  return (e - 1.0f) / (e + 1.0f);
}

// ---------------------------------------------------------------------------
// X0 (64,1024,512) fp32 -> XX0[t][n][c] hi/lo bf16, n = d*64+b, tau = 2t+d.
// ---------------------------------------------------------------------------
__global__ void prep_x0(const float* __restrict__ X0, unsigned short* __restrict__ XH) {
  unsigned short* XL = XH + 33554432;
  __shared__ float tile[32][65];
  const int b  = blockIdx.x;        // 0..63
  const int c0 = blockIdx.y * 32;   // 0..1023 step 32
  const int tid = threadIdx.x;      // 256
  for (int tb = 0; tb < 8; ++tb) {
    const int tau0 = tb * 64;
#pragma unroll
    for (int i = 0; i < 8; ++i) {
      const int cc  = (tid >> 6) + 4 * i;
      const int tau = tid & 63;
      tile[cc][tau] = X0[(size_t)b * 524288 + (size_t)(c0 + cc) * 512 + tau0 + tau];
    }
    __syncthreads();
#pragma unroll
    for (int s = 0; s < 8; ++s) {
      const int cc  = tid & 31;
      const int tau = (tid >> 5) * 8 + s;
      const int gt  = tau0 + tau;
      const int tt  = gt >> 1, d = gt & 1;
      unsigned short h, l;
      split_bf(tile[cc][tau], h, l);
      const size_t o = (size_t)tt * 131072 + (size_t)(d * 64 + b) * 1024 + c0 + cc;
      XH[o] = h; XL[o] = l;
    }
    __syncthreads();
  }
}

// ---------------------------------------------------------------------------
// X1 (64,512,96) fp32 -> XX1[t][n][h] hi/lo bf16, t<48, tau = 2t+d.
// ---------------------------------------------------------------------------
__global__ void prep_x1(const float* __restrict__ X1, unsigned short* __restrict__ XH) {
  unsigned short* XL = XH + 3145728;
  __shared__ float tile[32][97];
  const int b  = blockIdx.x;        // 0..63
  const int h0 = blockIdx.y * 32;   // 0..511 step 32
  const int tid = threadIdx.x;
#pragma unroll
  for (int i = 0; i < 12; ++i) {
    const int idx = i * 256 + tid;  // < 3072
    const int cc = idx / 96, tau = idx % 96;
    tile[cc][tau] = X1[(size_t)b * 49152 + (size_t)(h0 + cc) * 96 + tau];
  }
  __syncthreads();
#pragma unroll
  for (int i = 0; i < 12; ++i) {
    const int idx = i * 256 + tid;
    const int cc = idx & 31, tau = idx >> 5;  // tau 0..95
    const int tt = tau >> 1, d = tau & 1;
    unsigned short h, l;
    split_bf(tile[cc][tau], h, l);
    const size_t o = (size_t)tt * 65536 + (size_t)(d * 64 + b) * 512 + h0 + cc;
    XH[o] = h; XL[o] = l;
  }
}

// ---------------------------------------------------------------------------
// Persistent recurrent kernel. Grid = 256 blocks x 256 threads (1 WG/CU).
// ---------------------------------------------------------------------------
template <bool STAGED>
__launch_bounds__(256, 1)
__global__ void rnn_persistent(unsigned char* __restrict__ ws,
                               const float* __restrict__ X0, const float* __restrict__ X1,
                               const float* __restrict__ WihE, const float* __restrict__ WhhE,
                               const float* __restrict__ bihE, const float* __restrict__ bhhE,
                               const float* __restrict__ WihD, const float* __restrict__ WhhD,
                               const float* __restrict__ bihD, const float* __restrict__ bhhD,
                               float* __restrict__ out) {
  const int tid  = threadIdx.x;
  const int wave = tid >> 6;
  const int lane = tid & 63;
  const int l15  = lane & 15;
  const int quad = lane >> 4;

  const int g  = blockIdx.x & 7;   // group
  const int m  = blockIdx.x >> 3;  // member 0..31
  const int rb = g * 16;           // batch-row base of group
  const int ib = m * 16;           // hidden-i base of this member

  const unsigned short* XX0H = (const unsigned short*)(ws + OFF_XX0H);
  const unsigned short* XX0L = (const unsigned short*)(ws + OFF_XX0L);
  const unsigned short* XX1H = (const unsigned short*)(ws + OFF_XX1H);
  const unsigned short* XX1L = (const unsigned short*)(ws + OFF_XX1L);
  unsigned int* HbP = (unsigned int*)(ws + OFF_HB);      // [2][128][512] packed
  unsigned int* cnt = (unsigned int*)(ws + OFF_CNT) + (size_t)g * 16;

  __shared__ float red[4][6][256];  // 24 KB

  const int r_row = tid >> 4;   // batch row within group (gate phase)
  const int ii    = tid & 15;
  const int ig    = ib + ii;

  // A-operand addressing for the gh phase (row n = rb + l15)
  const int an   = rb + l15;          // group's batch rows
  const int ab   = an & 63, ad = an >> 6;   // original batch / dilation of A rows
  const int onrow = rb + r_row;
  const int ob = onrow & 63, od = onrow >> 6;

  const float bieR = bihE[ig], bieZ = bihE[512 + ig], bieN = bihE[1024 + ig];
  const float bheR = bhhE[ig], bheZ = bhhE[512 + ig], bheN = bhhE[1024 + ig];
  const float bidR = bihD[ig], bidZ = bihD[512 + ig], bidN = bihD[1024 + ig];
  const float bhdR = bhhD[ig], bhdZ = bhhD[512 + ig], bhdN = bhhD[1024 + ig];

  // ---- encoder weight fragments: fp32 -> hi/lo split in registers.
  // B-frag: element j holds W[n = nt*512 + ib + l15][k = ktile*32 + quad*8 + j]
  bf16x8 WIH_H[24], WIH_L[24], WHH_H[12], WHH_L[12];
#pragma unroll
  for (int kt = 0; kt < 8; ++kt)
#pragma unroll
    for (int nt = 0; nt < 3; ++nt)
      split8(WihE + (size_t)(nt * 512 + ib + l15) * 1024 + (wave * 8 + kt) * 32 + quad * 8,
             WIH_H[kt * 3 + nt], WIH_L[kt * 3 + nt]);
#pragma unroll
  for (int kt = 0; kt < 4; ++kt)
#pragma unroll
    for (int nt = 0; nt < 3; ++nt)
      split8(WhhE + (size_t)(nt * 512 + ib + l15) * 512 + (wave * 4 + kt) * 32 + quad * 8,
             WHH_H[kt * 3 + nt], WHH_L[kt * 3 + nt]);

  // ---- init h = 0 into parity-0 buffer, arrive
  float h_reg = 0.0f;
  __hip_atomic_store(HbP + (size_t)onrow * 512 + ig, 0u,
                     __ATOMIC_RELAXED, __HIP_MEMORY_SCOPE_AGENT);
  __syncthreads();
  if (tid == 0) {
    __hip_atomic_fetch_add(cnt, 1u, __ATOMIC_RELEASE, __HIP_MEMORY_SCOPE_AGENT);
  }
  unsigned int target = 32;

  // ===================== encoder: 256 steps =====================
  for (int t = 0; t < 256; ++t) {
    const int par  = t & 1;        // read h(t) from this parity
    const int wpar = (t + 1) & 1;  // write h(t+1) to the other

    // ---- gi = x[t] @ WihE^T  (independent of h; overlaps the sync wait)
    f32x4 gi0 = {0,0,0,0}, gi1 = {0,0,0,0}, gi2 = {0,0,0,0};
    const size_t xb  = ((size_t)t * 128 + an) * 1024 + quad * 8;  // staged
    const int    tau = 2 * t + ad;                                 // direct
#pragma unroll
    for (int kt = 0; kt < 8; ++kt) {
      bf16x8 axh, axl;
      if constexpr (STAGED) {
        axh = *reinterpret_cast<const bf16x8*>(XX0H + xb + (wave * 8 + kt) * 32);
        axl = *reinterpret_cast<const bf16x8*>(XX0L + xb + (wave * 8 + kt) * 32);
      } else {
        float xv[8];
#pragma unroll
        for (int j = 0; j < 8; ++j)
          xv[j] = X0[(size_t)ab * 524288 +
                     (size_t)((wave * 8 + kt) * 32 + quad * 8 + j) * 512 + tau];
        split8a(xv, axh, axl);
      }
      gi0 = MFMA16(axh, WIH_H[kt * 3 + 0], gi0);
      gi1 = MFMA16(axh, WIH_H[kt * 3 + 1], gi1);
      gi2 = MFMA16(axh, WIH_H[kt * 3 + 2], gi2);
      gi0 = MFMA16(axl, WIH_H[kt * 3 + 0], gi0);
      gi1 = MFMA16(axl, WIH_H[kt * 3 + 1], gi1);
      gi2 = MFMA16(axl, WIH_H[kt * 3 + 2], gi2);
      gi0 = MFMA16(axh, WIH_L[kt * 3 + 0], gi0);
      gi1 = MFMA16(axh, WIH_L[kt * 3 + 1], gi1);
      gi2 = MFMA16(axh, WIH_L[kt * 3 + 2], gi2);
    }

    // ---- wait for h(t) from all group members
    if (tid == 0) {
      while (__hip_atomic_load(cnt, __ATOMIC_ACQUIRE, __HIP_MEMORY_SCOPE_AGENT) < target) {}
    }
    __syncthreads();
    __builtin_amdgcn_fence(__ATOMIC_ACQUIRE, "agent");
    target += 32;

    // ---- gh = h @ WhhE^T  (h via relaxed agent atomics, parity buffer)
    const unsigned int* hrow = HbP + (size_t)par * 65536 + (size_t)an * 512 + quad * 8;
    f32x4 gh0 = {0,0,0,0}, gh1 = {0,0,0,0}, gh2 = {0,0,0,0};
#pragma unroll
    for (int kt = 0; kt < 4; ++kt) {
      bf16x8 ahh, ahl;
      load_h_frag(hrow + (wave * 4 + kt) * 32, ahh, ahl);
      gh0 = MFMA16(ahh, WHH_H[kt * 3 + 0], gh0);
      gh1 = MFMA16(ahh, WHH_H[kt * 3 + 1], gh1);
      gh2 = MFMA16(ahh, WHH_H[kt * 3 + 2], gh2);
      gh0 = MFMA16(ahl, WHH_H[kt * 3 + 0], gh0);
      gh1 = MFMA16(ahl, WHH_H[kt * 3 + 1], gh1);
      gh2 = MFMA16(ahl, WHH_H[kt * 3 + 2], gh2);
      gh0 = MFMA16(ahh, WHH_L[kt * 3 + 0], gh0);
      gh1 = MFMA16(ahh, WHH_L[kt * 3 + 1], gh1);
      gh2 = MFMA16(ahh, WHH_L[kt * 3 + 2], gh2);
    }

    // ---- reduce 4 wave-partials (C/D layout: row=quad*4+q, col=l15)
#pragma unroll
    for (int q = 0; q < 4; ++q) {
      const int base = (quad * 4 + q) * 16 + l15;
      red[wave][0][base] = gi0[q]; red[wave][1][base] = gi1[q]; red[wave][2][base] = gi2[q];
      red[wave][3][base] = gh0[q]; red[wave][4][base] = gh1[q]; red[wave][5][base] = gh2[q];
    }
    __syncthreads();
    float sR = 0, sZ = 0, sN = 0, hR = 0, hZ = 0, hN = 0;
#pragma unroll
    for (int w = 0; w < 4; ++w) {
      sR += red[w][0][tid]; sZ += red[w][1][tid]; sN += red[w][2][tid];
      hR += red[w][3][tid]; hZ += red[w][4][tid]; hN += red[w][5][tid];
    }
    const float rr = sigmoidf_(sR + bieR + hR + bheR);
    const float zz = sigmoidf_(sZ + bieZ + hZ + bheZ);
    const float nn = tanhf_(sN + bieN + rr * (hN + bheN));
    h_reg = (1.0f - zz) * nn + zz * h_reg;
    unsigned short ph, pl;
    split_bf(h_reg, ph, pl);
    __hip_atomic_store(HbP + (size_t)wpar * 65536 + (size_t)onrow * 512 + ig,
                       (unsigned int)ph | ((unsigned int)pl << 16),
                       __ATOMIC_RELAXED, __HIP_MEMORY_SCOPE_AGENT);
    __syncthreads();  // all threads' h stores happen-before tid0's release
    if (tid == 0) {
      __hip_atomic_fetch_add(cnt, 1u, __ATOMIC_RELEASE, __HIP_MEMORY_SCOPE_AGENT);
    }
  }

  // ===================== decoder weights (fp32 -> split, reuse regs) ========
  bf16x8 D1H[12], D1L[12], D2H[12], D2L[12], DHH[12], DHL[12];
#pragma unroll
  for (int kt = 0; kt < 4; ++kt)
#pragma unroll
    for (int nt = 0; nt < 3; ++nt) {
      const size_t row = (size_t)(nt * 512 + ib + l15);
      const int    k   = (wave * 4 + kt) * 32 + quad * 8;
      split8(WihD + row * 1024 + k,       D1H[kt * 3 + nt], D1L[kt * 3 + nt]);
      split8(WihD + row * 1024 + 512 + k, D2H[kt * 3 + nt], D2L[kt * 3 + nt]);
      split8(WhhD + row * 512 + k,        DHH[kt * 3 + nt], DHL[kt * 3 + nt]);
    }

  float* orow = out + (size_t)ob * 49152 + (size_t)ig * 96 + od;

  // ===================== decoder: 48 steps =====================
  for (int t = 0; t < 48; ++t) {
    const int par  = t & 1;        // 256 is even -> parity continues cleanly
    const int wpar = (t + 1) & 1;

    // ---- x1 part of gi (independent of h)
    f32x4 gi0 = {0,0,0,0}, gi1 = {0,0,0,0}, gi2 = {0,0,0,0};
    const size_t x1b = ((size_t)t * 128 + an) * 512 + quad * 8;  // staged
    const int    tau = 2 * t + ad;                                // direct, <= 95
#pragma unroll
    for (int kt = 0; kt < 4; ++kt) {
      bf16x8 axh, axl;
      if constexpr (STAGED) {
        axh = *reinterpret_cast<const bf16x8*>(XX1H + x1b + (wave * 4 + kt) * 32);
        axl = *reinterpret_cast<const bf16x8*>(XX1L + x1b + (wave * 4 + kt) * 32);
      } else {
        float xv[8];
#pragma unroll
        for (int j = 0; j < 8; ++j)
          xv[j] = X1[(size_t)ab * 49152 +
                     (size_t)((wave * 4 + kt) * 32 + quad * 8 + j) * 96 + tau];
        split8a(xv, axh, axl);
      }
      gi0 = MFMA16(axh, D2H[kt * 3 + 0], gi0);
      gi1 = MFMA16(axh, D2H[kt * 3 + 1], gi1);
      gi2 = MFMA16(axh, D2H[kt * 3 + 2], gi2);
      gi0 = MFMA16(axl, D2H[kt * 3 + 0], gi0);
      gi1 = MFMA16(axl, D2H[kt * 3 + 1], gi1);
      gi2 = MFMA16(axl, D2H[kt * 3 + 2], gi2);
      gi0 = MFMA16(axh, D2L[kt * 3 + 0], gi0);
      gi1 = MFMA16(axh, D2L[kt * 3 + 1], gi1);
      gi2 = MFMA16(axh, D2L[kt * 3 + 2], gi2);
    }

    if (tid == 0) {
      while (__hip_atomic_load(cnt, __ATOMIC_ACQUIRE, __HIP_MEMORY_SCOPE_AGENT) < target) {}
    }
    __syncthreads();
    __builtin_amdgcn_fence(__ATOMIC_ACQUIRE, "agent");
    target += 32;

    // ---- h parts: gi += h@Wd1^T (din == h), gh = h@WhhD^T
    const unsigned int* hrow = HbP + (size_t)par * 65536 + (size_t)an * 512 + quad * 8;
    f32x4 gh0 = {0,0,0,0}, gh1 = {0,0,0,0}, gh2 = {0,0,0,0};
#pragma unroll
    for (int kt = 0; kt < 4; ++kt) {
      bf16x8 ahh, ahl;
      load_h_frag(hrow + (wave * 4 + kt) * 32, ahh, ahl);
      gi0 = MFMA16(ahh, D1H[kt * 3 + 0], gi0);
      gi1 = MFMA16(ahh, D1H[kt * 3 + 1], gi1);
      gi2 = MFMA16(ahh, D1H[kt * 3 + 2], gi2);
      gi0 = MFMA16(ahl, D1H[kt * 3 + 0], gi0);
      gi1 = MFMA16(ahl, D1H[kt * 3 + 1], gi1);
      gi2 = MFMA16(ahl, D1H[kt * 3 + 2], gi2);
      gi0 = MFMA16(ahh, D1L[kt * 3 + 0], gi0);
      gi1 = MFMA16(ahh, D1L[kt * 3 + 1], gi1);
      gi2 = MFMA16(ahh, D1L[kt * 3 + 2], gi2);
      gh0 = MFMA16(ahh, DHH[kt * 3 + 0], gh0);
      gh1 = MFMA16(ahh, DHH[kt * 3 + 1], gh1);
      gh2 = MFMA16(ahh, DHH[kt * 3 + 2], gh2);
      gh0 = MFMA16(ahl, DHH[kt * 3 + 0], gh0);
      gh1 = MFMA16(ahl, DHH[kt * 3 + 1], gh1);
      gh2 = MFMA16(ahl, DHH[kt * 3 + 2], gh2);
      gh0 = MFMA16(ahh, DHL[kt * 3 + 0], gh0);
      gh1 = MFMA16(ahh, DHL[kt * 3 + 1], gh1);
      gh2 = MFMA16(ahh, DHL[kt * 3 + 2], gh2);
    }

#pragma unroll
    for (int q = 0; q < 4; ++q) {
      const int base = (quad * 4 + q) * 16 + l15;
      red[wave][0][base] = gi0[q]; red[wave][1][base] = gi1[q]; red[wave][2][base] = gi2[q];
      red[wave][3][base] = gh0[q]; red[wave][4][base] = gh1[q]; red[wave][5][base] = gh2[q];
    }
    __syncthreads();
    float sR = 0, sZ = 0, sN = 0, hR = 0, hZ = 0, hN = 0;
#pragma unroll
    for (int w = 0; w < 4; ++w) {
      sR += red[w][0][tid]; sZ += red[w][1][tid]; sN += red[w][2][tid];
      hR += red[w][3][tid]; hZ += red[w][4][tid]; hN += red[w][5][tid];
    }
    const float rr = sigmoidf_(sR + bidR + hR + bhdR);
    const float zz = sigmoidf_(sZ + bidZ + hZ + bhdZ);
    const float nn = tanhf_(sN + bidN + rr * (hN + bhdN));
    h_reg = (1.0f - zz) * nn + zz * h_reg;
    unsigned short ph, pl;
    split_bf(h_reg, ph, pl);
    __hip_atomic_store(HbP + (size_t)wpar * 65536 + (size_t)onrow * 512 + ig,
                       (unsigned int)ph | ((unsigned int)pl << 16),
                       __ATOMIC_RELAXED, __HIP_MEMORY_SCOPE_AGENT);
    orow[2 * t] = h_reg;  // o[b][ig][2t+d]
    __syncthreads();
    if (t < 47 && tid == 0) {
      __hip_atomic_fetch_add(cnt, 1u, __ATOMIC_RELEASE, __HIP_MEMORY_SCOPE_AGENT);
    }
  }
}

extern "C" void kernel_launch(void* const* d_in, const int* in_sizes, int n_in,
                              void* d_out, int out_size, void* d_ws, size_t ws_size,
                              hipStream_t stream) {
  (void)in_sizes; (void)n_in; (void)out_size;
  const float* X0   = (const float*)d_in[0];
  const float* X1   = (const float*)d_in[1];
  // d_in[2] = seqlen (unused, fixed 512)
  const float* WihE = (const float*)d_in[3];
  const float* WhhE = (const float*)d_in[4];
  const float* bihE = (const float*)d_in[5];
  const float* bhhE = (const float*)d_in[6];
  const float* WihD = (const float*)d_in[7];
  const float* WhhD = (const float*)d_in[8];
  const float* bihD = (const float*)d_in[9];
  const float* bhhD = (const float*)d_in[10];
  unsigned char* ws = (unsigned char*)d_ws;

  // ws_size is constant across calls -> branch is graph-capture-safe.
  const bool staged = (ws_size >= NEED_FULL);

  hipMemsetAsync(ws + OFF_CNT, 0, 512, stream);
  if (staged) {
    prep_x0<<<dim3(64, 32), 256, 0, stream>>>(X0, (unsigned short*)(ws + OFF_XX0H));
    prep_x1<<<dim3(64, 16), 256, 0, stream>>>(X1, (unsigned short*)(ws + OFF_XX1H));
    rnn_persistent<true><<<256, 256, 0, stream>>>(ws, X0, X1, WihE, WhhE, bihE, bhhE,
                                                  WihD, WhhD, bihD, bhhD, (float*)d_out);
  } else {
    rnn_persistent<false><<<256, 256, 0, stream>>>(ws, X0, X1, WihE, WhhE, bihE, bhhE,
                                                   WihD, WhhD, bihD, bhhD, (float*)d_out);
  }
}

// Round 4
// 4963.202 us; speedup vs baseline: 1.2275x; 1.2275x over previous
//
#include <hip/hip_runtime.h>

// ============================================================================
// Dilated GRU encoder-decoder, persistent-kernel design for MI355X. Round 4.
//
// Round 3 passed (absmax 3.9e-3) at 5880 us = 19.3 us/step: pure sync latency
// (MfmaUtil 3.7%, VALUBusy 2.9%, HBM 0.8%). Round 4 rebuilds the sync:
//  - per-member FLAGS (own 64B line each) instead of one contended counter:
//    arrival = release fence + relaxed atomic STORE (no RMW serialization).
//  - every wave polls all 32 group flags in parallel (lanes 0..31) with
//    relaxed loads + one acquire fence on exit; no tid0 spin, no extra
//    barrier hop.
//  - h-fragment atomic loads issued all up-front (1 latency round, not 4).
// Unchanged from r3 (proven): parity double-buffered h as packed u32
// {bf16 hi | bf16 lo} relaxed agent atomics, register-resident split-bf16
// weights, 3-term Markidis MFMAs, gi computed before the wait.
// ============================================================================

typedef __bf16 bf16x8 __attribute__((ext_vector_type(8)));
typedef float  f32x4  __attribute__((ext_vector_type(4)));

#define MFMA16(a, b, c) __builtin_amdgcn_mfma_f32_16x16x32_bf16(a, b, c, 0, 0, 0)

// ---- workspace byte offsets ------------------------------------------------
#define OFF_FLG   0ULL          // 8 groups * 32 members * 64 B = 16384
#define OFF_HB    16384ULL      // 2 * 128 * 512 * 4 B (packed u32, dbuf)
#define OFF_XX0H  540672ULL     // 256*128*1024 bf16 = 67108864 B
#define OFF_XX0L  67649536ULL
#define OFF_XX1H  134758400ULL  // 48*128*512 bf16 = 6291456 B
#define OFF_XX1L  141049856ULL
#define NEED_FULL 147341312ULL  // staged path requires this many ws bytes

static __device__ __forceinline__ void split_bf(float x, unsigned short& hi,
                                                unsigned short& lo) {
  union { __bf16 b; unsigned short u; } c;
  c.b = (__bf16)x; hi = c.u;
  float fh = (float)c.b;
  c.b = (__bf16)(x - fh); lo = c.u;
}
static __device__ __forceinline__ void split8(const float* __restrict__ p,
                                              bf16x8& h, bf16x8& l) {
#pragma unroll
  for (int j = 0; j < 8; ++j) {
    const float x = p[j];
    const __bf16 hb = (__bf16)x;
    h[j] = hb;
    l[j] = (__bf16)(x - (float)hb);
  }
}
static __device__ __forceinline__ void split8a(const float* xv, bf16x8& h, bf16x8& l) {
#pragma unroll
  for (int j = 0; j < 8; ++j) {
    const float x = xv[j];
    const __bf16 hb = (__bf16)x;
    h[j] = hb;
    l[j] = (__bf16)(x - (float)hb);
  }
}
static __device__ __forceinline__ float sigmoidf_(float x) {
  return 1.0f / (1.0f + __expf(-x));
}
static __device__ __forceinline__ float tanhf_(float x) {
  x = fminf(fmaxf(x, -15.0f), 15.0f);
  float e = __expf(2.0f * x);
  return (e - 1.0f) / (e + 1.0f);
}

// Wait until all 32 member flags of this group reach tgt. Called by EVERY
// wave independently; lanes 0..31 poll member lanes' flags (each on its own
// 64B line) with relaxed agent atomics; single acquire fence on exit.
static __device__ __forceinline__ void wait_group(const unsigned int* __restrict__ flg,
                                                  int lane, unsigned int tgt) {
  for (;;) {
    unsigned int v = tgt;
    if (lane < 32)
      v = __hip_atomic_load(flg + lane * 16, __ATOMIC_RELAXED, __HIP_MEMORY_SCOPE_AGENT);
    if (__all((int)(v >= tgt))) break;
  }
  __builtin_amdgcn_fence(__ATOMIC_ACQUIRE, "agent");
}

// ---------------------------------------------------------------------------
// X0 (64,1024,512) fp32 -> XX0[t][n][c] hi/lo bf16, n = d*64+b, tau = 2t+d.
// ---------------------------------------------------------------------------
__global__ void prep_x0(const float* __restrict__ X0, unsigned short* __restrict__ XH) {
  unsigned short* XL = XH + 33554432;
  __shared__ float tile[32][65];
  const int b  = blockIdx.x;        // 0..63
  const int c0 = blockIdx.y * 32;   // 0..1023 step 32
  const int tid = threadIdx.x;      // 256
  for (int tb = 0; tb < 8; ++tb) {
    const int tau0 = tb * 64;
#pragma unroll
    for (int i = 0; i < 8; ++i) {
      const int cc  = (tid >> 6) + 4 * i;
      const int tau = tid & 63;
      tile[cc][tau] = X0[(size_t)b * 524288 + (size_t)(c0 + cc) * 512 + tau0 + tau];
    }
    __syncthreads();
#pragma unroll
    for (int s = 0; s < 8; ++s) {
      const int cc  = tid & 31;
      const int tau = (tid >> 5) * 8 + s;
      const int gt  = tau0 + tau;
      const int tt  = gt >> 1, d = gt & 1;
      unsigned short h, l;
      split_bf(tile[cc][tau], h, l);
      const size_t o = (size_t)tt * 131072 + (size_t)(d * 64 + b) * 1024 + c0 + cc;
      XH[o] = h; XL[o] = l;
    }
    __syncthreads();
  }
}

// ---------------------------------------------------------------------------
// X1 (64,512,96) fp32 -> XX1[t][n][h] hi/lo bf16, t<48, tau = 2t+d.
// ---------------------------------------------------------------------------
__global__ void prep_x1(const float* __restrict__ X1, unsigned short* __restrict__ XH) {
  unsigned short* XL = XH + 3145728;
  __shared__ float tile[32][97];
  const int b  = blockIdx.x;        // 0..63
  const int h0 = blockIdx.y * 32;   // 0..511 step 32
  const int tid = threadIdx.x;
#pragma unroll
  for (int i = 0; i < 12; ++i) {
    const int idx = i * 256 + tid;  // < 3072
    const int cc = idx / 96, tau = idx % 96;
    tile[cc][tau] = X1[(size_t)b * 49152 + (size_t)(h0 + cc) * 96 + tau];
  }
  __syncthreads();
#pragma unroll
  for (int i = 0; i < 12; ++i) {
    const int idx = i * 256 + tid;
    const int cc = idx & 31, tau = idx >> 5;  // tau 0..95
    const int tt = tau >> 1, d = tau & 1;
    unsigned short h, l;
    split_bf(tile[cc][tau], h, l);
    const size_t o = (size_t)tt * 65536 + (size_t)(d * 64 + b) * 512 + h0 + cc;
    XH[o] = h; XL[o] = l;
  }
}

// ---------------------------------------------------------------------------
// Persistent recurrent kernel. Grid = 256 blocks x 256 threads (1 WG/CU).
// ---------------------------------------------------------------------------
template <bool STAGED>
__launch_bounds__(256, 1)
__global__ void rnn_persistent(unsigned char* __restrict__ ws,
                               const float* __restrict__ X0, const float* __restrict__ X1,
                               const float* __restrict__ WihE, const float* __restrict__ WhhE,
                               const float* __restrict__ bihE, const float* __restrict__ bhhE,
                               const float* __restrict__ WihD, const float* __restrict__ WhhD,
                               const float* __restrict__ bihD, const float* __restrict__ bhhD,
                               float* __restrict__ out) {
  const int tid  = threadIdx.x;
  const int wave = tid >> 6;
  const int lane = tid & 63;
  const int l15  = lane & 15;
  const int quad = lane >> 4;

  const int g  = blockIdx.x & 7;   // group
  const int m  = blockIdx.x >> 3;  // member 0..31
  const int rb = g * 16;           // batch-row base of group
  const int ib = m * 16;           // hidden-i base of this member

  const unsigned short* XX0H = (const unsigned short*)(ws + OFF_XX0H);
  const unsigned short* XX0L = (const unsigned short*)(ws + OFF_XX0L);
  const unsigned short* XX1H = (const unsigned short*)(ws + OFF_XX1H);
  const unsigned short* XX1L = (const unsigned short*)(ws + OFF_XX1L);
  unsigned int* HbP  = (unsigned int*)(ws + OFF_HB);   // [2][128][512] packed
  unsigned int* flg  = (unsigned int*)(ws + OFF_FLG) + (size_t)g * 512;  // 32 * 16 u32
  unsigned int* myfl = flg + (size_t)m * 16;

  __shared__ float red[4][6][256];  // 24 KB

  const int r_row = tid >> 4;   // batch row within group (gate phase)
  const int ii    = tid & 15;
  const int ig    = ib + ii;

  const int an    = rb + l15;               // A-operand batch row
  const int ab    = an & 63, ad = an >> 6;  // original batch / dilation
  const int onrow = rb + r_row;
  const int ob    = onrow & 63, od = onrow >> 6;

  const float bieR = bihE[ig], bieZ = bihE[512 + ig], bieN = bihE[1024 + ig];
  const float bheR = bhhE[ig], bheZ = bhhE[512 + ig], bheN = bhhE[1024 + ig];
  const float bidR = bihD[ig], bidZ = bihD[512 + ig], bidN = bihD[1024 + ig];
  const float bhdR = bhhD[ig], bhdZ = bhhD[512 + ig], bhdN = bhhD[1024 + ig];

  // ---- encoder weight fragments: fp32 -> hi/lo split in registers.
  bf16x8 WIH_H[24], WIH_L[24], WHH_H[12], WHH_L[12];
#pragma unroll
  for (int kt = 0; kt < 8; ++kt)
#pragma unroll
    for (int nt = 0; nt < 3; ++nt)
      split8(WihE + (size_t)(nt * 512 + ib + l15) * 1024 + (wave * 8 + kt) * 32 + quad * 8,
             WIH_H[kt * 3 + nt], WIH_L[kt * 3 + nt]);
#pragma unroll
  for (int kt = 0; kt < 4; ++kt)
#pragma unroll
    for (int nt = 0; nt < 3; ++nt)
      split8(WhhE + (size_t)(nt * 512 + ib + l15) * 512 + (wave * 4 + kt) * 32 + quad * 8,
             WHH_H[kt * 3 + nt], WHH_L[kt * 3 + nt]);

  // ---- init h(0) = 0 into parity-0 buffer, publish (flag value = 1)
  float h_reg = 0.0f;
  __hip_atomic_store(HbP + (size_t)onrow * 512 + ig, 0u,
                     __ATOMIC_RELAXED, __HIP_MEMORY_SCOPE_AGENT);
  __syncthreads();
  if (tid == 0) {
    __builtin_amdgcn_fence(__ATOMIC_RELEASE, "agent");
    __hip_atomic_store(myfl, 1u, __ATOMIC_RELAXED, __HIP_MEMORY_SCOPE_AGENT);
  }

  // ===================== encoder: 256 steps =====================
  for (int t = 0; t < 256; ++t) {
    const int par  = t & 1;
    const int wpar = (t + 1) & 1;

    // ---- gi = x[t] @ WihE^T  (independent of h; overlaps the wait)
    f32x4 gi0 = {0,0,0,0}, gi1 = {0,0,0,0}, gi2 = {0,0,0,0};
    const size_t xb  = ((size_t)t * 128 + an) * 1024 + quad * 8;  // staged
    const int    tau = 2 * t + ad;                                 // direct
#pragma unroll
    for (int kt = 0; kt < 8; ++kt) {
      bf16x8 axh, axl;
      if constexpr (STAGED) {
        axh = *reinterpret_cast<const bf16x8*>(XX0H + xb + (wave * 8 + kt) * 32);
        axl = *reinterpret_cast<const bf16x8*>(XX0L + xb + (wave * 8 + kt) * 32);
      } else {
        float xv[8];
#pragma unroll
        for (int j = 0; j < 8; ++j)
          xv[j] = X0[(size_t)ab * 524288 +
                     (size_t)((wave * 8 + kt) * 32 + quad * 8 + j) * 512 + tau];
        split8a(xv, axh, axl);
      }
      gi0 = MFMA16(axh, WIH_H[kt * 3 + 0], gi0);
      gi1 = MFMA16(axh, WIH_H[kt * 3 + 1], gi1);
      gi2 = MFMA16(axh, WIH_H[kt * 3 + 2], gi2);
      gi0 = MFMA16(axl, WIH_H[kt * 3 + 0], gi0);
      gi1 = MFMA16(axl, WIH_H[kt * 3 + 1], gi1);
      gi2 = MFMA16(axl, WIH_H[kt * 3 + 2], gi2);
      gi0 = MFMA16(axh, WIH_L[kt * 3 + 0], gi0);
      gi1 = MFMA16(axh, WIH_L[kt * 3 + 1], gi1);
      gi2 = MFMA16(axh, WIH_L[kt * 3 + 2], gi2);
    }

    // ---- wait for h(t) from all group members (per-wave, parallel poll)
    wait_group(flg, lane, (unsigned int)(t + 1));

    // ---- load all h fragments up front (1 latency round), then MFMA
    const unsigned int* hrow = HbP + (size_t)par * 65536 + (size_t)an * 512 + quad * 8;
    unsigned int hw[4][8];
#pragma unroll
    for (int kt = 0; kt < 4; ++kt)
#pragma unroll
      for (int j = 0; j < 8; ++j)
        hw[kt][j] = __hip_atomic_load(hrow + (wave * 4 + kt) * 32 + j,
                                      __ATOMIC_RELAXED, __HIP_MEMORY_SCOPE_AGENT);
    f32x4 gh0 = {0,0,0,0}, gh1 = {0,0,0,0}, gh2 = {0,0,0,0};
#pragma unroll
    for (int kt = 0; kt < 4; ++kt) {
      bf16x8 ahh, ahl;
      union { unsigned short u; __bf16 b; } c;
#pragma unroll
      for (int j = 0; j < 8; ++j) {
        c.u = (unsigned short)(hw[kt][j] & 0xffffu); ahh[j] = c.b;
        c.u = (unsigned short)(hw[kt][j] >> 16);     ahl[j] = c.b;
      }
      gh0 = MFMA16(ahh, WHH_H[kt * 3 + 0], gh0);
      gh1 = MFMA16(ahh, WHH_H[kt * 3 + 1], gh1);
      gh2 = MFMA16(ahh, WHH_H[kt * 3 + 2], gh2);
      gh0 = MFMA16(ahl, WHH_H[kt * 3 + 0], gh0);
      gh1 = MFMA16(ahl, WHH_H[kt * 3 + 1], gh1);
      gh2 = MFMA16(ahl, WHH_H[kt * 3 + 2], gh2);
      gh0 = MFMA16(ahh, WHH_L[kt * 3 + 0], gh0);
      gh1 = MFMA16(ahh, WHH_L[kt * 3 + 1], gh1);
      gh2 = MFMA16(ahh, WHH_L[kt * 3 + 2], gh2);
    }

    // ---- reduce 4 wave-partials (C/D layout: row=quad*4+q, col=l15)
#pragma unroll
    for (int q = 0; q < 4; ++q) {
      const int base = (quad * 4 + q) * 16 + l15;
      red[wave][0][base] = gi0[q]; red[wave][1][base] = gi1[q]; red[wave][2][base] = gi2[q];
      red[wave][3][base] = gh0[q]; red[wave][4][base] = gh1[q]; red[wave][5][base] = gh2[q];
    }
    __syncthreads();
    float sR = 0, sZ = 0, sN = 0, hR = 0, hZ = 0, hN = 0;
#pragma unroll
    for (int w = 0; w < 4; ++w) {
      sR += red[w][0][tid]; sZ += red[w][1][tid]; sN += red[w][2][tid];
      hR += red[w][3][tid]; hZ += red[w][4][tid]; hN += red[w][5][tid];
    }
    const float rr = sigmoidf_(sR + bieR + hR + bheR);
    const float zz = sigmoidf_(sZ + bieZ + hZ + bheZ);
    const float nn = tanhf_(sN + bieN + rr * (hN + bheN));
    h_reg = (1.0f - zz) * nn + zz * h_reg;
    unsigned short ph, pl;
    split_bf(h_reg, ph, pl);
    __hip_atomic_store(HbP + (size_t)wpar * 65536 + (size_t)onrow * 512 + ig,
                       (unsigned int)ph | ((unsigned int)pl << 16),
                       __ATOMIC_RELAXED, __HIP_MEMORY_SCOPE_AGENT);
    __syncthreads();  // all threads' h stores precede the release/flag
    if (tid == 0) {
      __builtin_amdgcn_fence(__ATOMIC_RELEASE, "agent");
      __hip_atomic_store(myfl, (unsigned int)(t + 2),
                         __ATOMIC_RELAXED, __HIP_MEMORY_SCOPE_AGENT);
    }
  }

  // ===================== decoder weights (fp32 -> split, reuse regs) ========
  bf16x8 D1H[12], D1L[12], D2H[12], D2L[12], DHH[12], DHL[12];
#pragma unroll
  for (int kt = 0; kt < 4; ++kt)
#pragma unroll
    for (int nt = 0; nt < 3; ++nt) {
      const size_t row = (size_t)(nt * 512 + ib + l15);
      const int    k   = (wave * 4 + kt) * 32 + quad * 8;
      split8(WihD + row * 1024 + k,       D1H[kt * 3 + nt], D1L[kt * 3 + nt]);
      split8(WihD + row * 1024 + 512 + k, D2H[kt * 3 + nt], D2L[kt * 3 + nt]);
      split8(WhhD + row * 512 + k,        DHH[kt * 3 + nt], DHL[kt * 3 + nt]);
    }

  float* orow = out + (size_t)ob * 49152 + (size_t)ig * 96 + od;

  // ===================== decoder: 48 steps (global step gt = 256 + t) =======
  for (int t = 0; t < 48; ++t) {
    const int gt   = 256 + t;
    const int par  = gt & 1;
    const int wpar = (gt + 1) & 1;

    // ---- x1 part of gi (independent of h)
    f32x4 gi0 = {0,0,0,0}, gi1 = {0,0,0,0}, gi2 = {0,0,0,0};
    const size_t x1b = ((size_t)t * 128 + an) * 512 + quad * 8;  // staged
    const int    tau = 2 * t + ad;                                // direct
#pragma unroll
    for (int kt = 0; kt < 4; ++kt) {
      bf16x8 axh, axl;
      if constexpr (STAGED) {
        axh = *reinterpret_cast<const bf16x8*>(XX1H + x1b + (wave * 4 + kt) * 32);
        axl = *reinterpret_cast<const bf16x8*>(XX1L + x1b + (wave * 4 + kt) * 32);
      } else {
        float xv[8];
#pragma unroll
        for (int j = 0; j < 8; ++j)
          xv[j] = X1[(size_t)ab * 49152 +
                     (size_t)((wave * 4 + kt) * 32 + quad * 8 + j) * 96 + tau];
        split8a(xv, axh, axl);
      }
      gi0 = MFMA16(axh, D2H[kt * 3 + 0], gi0);
      gi1 = MFMA16(axh, D2H[kt * 3 + 1], gi1);
      gi2 = MFMA16(axh, D2H[kt * 3 + 2], gi2);
      gi0 = MFMA16(axl, D2H[kt * 3 + 0], gi0);
      gi1 = MFMA16(axl, D2H[kt * 3 + 1], gi1);
      gi2 = MFMA16(axl, D2H[kt * 3 + 2], gi2);
      gi0 = MFMA16(axh, D2L[kt * 3 + 0], gi0);
      gi1 = MFMA16(axh, D2L[kt * 3 + 1], gi1);
      gi2 = MFMA16(axh, D2L[kt * 3 + 2], gi2);
    }

    wait_group(flg, lane, (unsigned int)(gt + 1));

    // ---- h parts: gi += h@Wd1^T (din == h), gh = h@WhhD^T
    const unsigned int* hrow = HbP + (size_t)par * 65536 + (size_t)an * 512 + quad * 8;
    unsigned int hw[4][8];
#pragma unroll
    for (int kt = 0; kt < 4; ++kt)
#pragma unroll
      for (int j = 0; j < 8; ++j)
        hw[kt][j] = __hip_atomic_load(hrow + (wave * 4 + kt) * 32 + j,
                                      __ATOMIC_RELAXED, __HIP_MEMORY_SCOPE_AGENT);
    f32x4 gh0 = {0,0,0,0}, gh1 = {0,0,0,0}, gh2 = {0,0,0,0};
#pragma unroll
    for (int kt = 0; kt < 4; ++kt) {
      bf16x8 ahh, ahl;
      union { unsigned short u; __bf16 b; } c;
#pragma unroll
      for (int j = 0; j < 8; ++j) {
        c.u = (unsigned short)(hw[kt][j] & 0xffffu); ahh[j] = c.b;
        c.u = (unsigned short)(hw[kt][j] >> 16);     ahl[j] = c.b;
      }
      gi0 = MFMA16(ahh, D1H[kt * 3 + 0], gi0);
      gi1 = MFMA16(ahh, D1H[kt * 3 + 1], gi1);
      gi2 = MFMA16(ahh, D1H[kt * 3 + 2], gi2);
      gi0 = MFMA16(ahl, D1H[kt * 3 + 0], gi0);
      gi1 = MFMA16(ahl, D1H[kt * 3 + 1], gi1);
      gi2 = MFMA16(ahl, D1H[kt * 3 + 2], gi2);
      gi0 = MFMA16(ahh, D1L[kt * 3 + 0], gi0);
      gi1 = MFMA16(ahh, D1L[kt * 3 + 1], gi1);
      gi2 = MFMA16(ahh, D1L[kt * 3 + 2], gi2);
      gh0 = MFMA16(ahh, DHH[kt * 3 + 0], gh0);
      gh1 = MFMA16(ahh, DHH[kt * 3 + 1], gh1);
      gh2 = MFMA16(ahh, DHH[kt * 3 + 2], gh2);
      gh0 = MFMA16(ahl, DHH[kt * 3 + 0], gh0);
      gh1 = MFMA16(ahl, DHH[kt * 3 + 1], gh1);
      gh2 = MFMA16(ahl, DHH[kt * 3 + 2], gh2);
      gh0 = MFMA16(ahh, DHL[kt * 3 + 0], gh0);
      gh1 = MFMA16(ahh, DHL[kt * 3 + 1], gh1);
      gh2 = MFMA16(ahh, DHL[kt * 3 + 2], gh2);
    }

#pragma unroll
    for (int q = 0; q < 4; ++q) {
      const int base = (quad * 4 + q) * 16 + l15;
      red[wave][0][base] = gi0[q]; red[wave][1][base] = gi1[q]; red[wave][2][base] = gi2[q];
      red[wave][3][base] = gh0[q]; red[wave][4][base] = gh1[q]; red[wave][5][base] = gh2[q];
    }
    __syncthreads();
    float sR = 0, sZ = 0, sN = 0, hR = 0, hZ = 0, hN = 0;
#pragma unroll
    for (int w = 0; w < 4; ++w) {
      sR += red[w][0][tid]; sZ += red[w][1][tid]; sN += red[w][2][tid];
      hR += red[w][3][tid]; hZ += red[w][4][tid]; hN += red[w][5][tid];
    }
    const float rr = sigmoidf_(sR + bidR + hR + bhdR);
    const float zz = sigmoidf_(sZ + bidZ + hZ + bhdZ);
    const float nn = tanhf_(sN + bidN + rr * (hN + bhdN));
    h_reg = (1.0f - zz) * nn + zz * h_reg;
    unsigned short ph, pl;
    split_bf(h_reg, ph, pl);
    __hip_atomic_store(HbP + (size_t)wpar * 65536 + (size_t)onrow * 512 + ig,
                       (unsigned int)ph | ((unsigned int)pl << 16),
                       __ATOMIC_RELAXED, __HIP_MEMORY_SCOPE_AGENT);
    orow[2 * t] = h_reg;  // o[b][ig][2t+d]
    __syncthreads();
    if (t < 47 && tid == 0) {
      __builtin_amdgcn_fence(__ATOMIC_RELEASE, "agent");
      __hip_atomic_store(myfl, (unsigned int)(gt + 2),
                         __ATOMIC_RELAXED, __HIP_MEMORY_SCOPE_AGENT);
    }
  }
}

extern "C" void kernel_launch(void* const* d_in, const int* in_sizes, int n_in,
                              void* d_out, int out_size, void* d_ws, size_t ws_size,
                              hipStream_t stream) {
  (void)in_sizes; (void)n_in; (void)out_size;
  const float* X0   = (const float*)d_in[0];
  const float* X1   = (const float*)d_in[1];
  // d_in[2] = seqlen (unused, fixed 512)
  const float* WihE = (const float*)d_in[3];
  const float* WhhE = (const float*)d_in[4];
  const float* bihE = (const float*)d_in[5];
  const float* bhhE = (const float*)d_in[6];
  const float* WihD = (const float*)d_in[7];
  const float* WhhD = (const float*)d_in[8];
  const float* bihD = (const float*)d_in[9];
  const float* bhhD = (const float*)d_in[10];
  unsigned char* ws = (unsigned char*)d_ws;

  const bool staged = (ws_size >= NEED_FULL);  // ws_size constant -> graph-safe

  hipMemsetAsync(ws + OFF_FLG, 0, 16384, stream);
  if (staged) {
    prep_x0<<<dim3(64, 32), 256, 0, stream>>>(X0, (unsigned short*)(ws + OFF_XX0H));
    prep_x1<<<dim3(64, 16), 256, 0, stream>>>(X1, (unsigned short*)(ws + OFF_XX1H));
    rnn_persistent<true><<<256, 256, 0, stream>>>(ws, X0, X1, WihE, WhhE, bihE, bhhE,
                                                  WihD, WhhD, bihD, bhhD, (float*)d_out);
  } else {
    rnn_persistent<false><<<256, 256, 0, stream>>>(ws, X0, X1, WihE, WhhE, bihE, bhhE,
                                                   WihD, WhhD, bihD, bhhD, (float*)d_out);
  }
}

// Round 5
// 4853.473 us; speedup vs baseline: 1.2553x; 1.0226x over previous
//
#include <hip/hip_runtime.h>

// ============================================================================
// Dilated GRU encoder-decoder, persistent-kernel design for MI355X. Round 5.
//
// r4 post-mortem: sync-primitive rebuild gave only 1.19x -> dominant cost is
// shared by r3/r4: (a) poll storm — every wave of every WG spinning on
// agent-scope atomic loads with no backoff congests the coherence point,
// delaying the h/flag stores being polled for; (b) h loads issued as 32
// scalar atomic dwords/thread when plain vectorized loads after the acquire
// fence are equally correct.
// Round 5: wave0-only polling with s_sleep backoff (others wait at barrier);
// plain uint4 h loads after the fence. Protocol (parity dbuf + per-member
// flag lines + release fence) unchanged — proven at absmax 3.9e-3.
// ============================================================================

typedef __bf16 bf16x8 __attribute__((ext_vector_type(8)));
typedef float  f32x4  __attribute__((ext_vector_type(4)));
typedef unsigned int u32x4 __attribute__((ext_vector_type(4)));

#define MFMA16(a, b, c) __builtin_amdgcn_mfma_f32_16x16x32_bf16(a, b, c, 0, 0, 0)

// ---- workspace byte offsets ------------------------------------------------
#define OFF_FLG   0ULL          // 8 groups * 32 members * 64 B = 16384
#define OFF_HB    16384ULL      // 2 * 128 * 512 * 4 B (packed u32, dbuf)
#define OFF_XX0H  540672ULL     // 256*128*1024 bf16 = 67108864 B
#define OFF_XX0L  67649536ULL
#define OFF_XX1H  134758400ULL  // 48*128*512 bf16 = 6291456 B
#define OFF_XX1L  141049856ULL
#define NEED_FULL 147341312ULL  // staged path requires this many ws bytes

static __device__ __forceinline__ void split_bf(float x, unsigned short& hi,
                                                unsigned short& lo) {
  union { __bf16 b; unsigned short u; } c;
  c.b = (__bf16)x; hi = c.u;
  float fh = (float)c.b;
  c.b = (__bf16)(x - fh); lo = c.u;
}
static __device__ __forceinline__ void split8(const float* __restrict__ p,
                                              bf16x8& h, bf16x8& l) {
#pragma unroll
  for (int j = 0; j < 8; ++j) {
    const float x = p[j];
    const __bf16 hb = (__bf16)x;
    h[j] = hb;
    l[j] = (__bf16)(x - (float)hb);
  }
}
static __device__ __forceinline__ void split8a(const float* xv, bf16x8& h, bf16x8& l) {
#pragma unroll
  for (int j = 0; j < 8; ++j) {
    const float x = xv[j];
    const __bf16 hb = (__bf16)x;
    h[j] = hb;
    l[j] = (__bf16)(x - (float)hb);
  }
}
static __device__ __forceinline__ float sigmoidf_(float x) {
  return 1.0f / (1.0f + __expf(-x));
}
static __device__ __forceinline__ float tanhf_(float x) {
  x = fminf(fmaxf(x, -15.0f), 15.0f);
  float e = __expf(2.0f * x);
  return (e - 1.0f) / (e + 1.0f);
}

// Wave 0 polls the 32 member flags (lane i -> member i's own 64B line) with
// relaxed agent atomics + s_sleep backoff; all waves then sync and fence.
static __device__ __forceinline__ void wait_group(const unsigned int* __restrict__ flg,
                                                  int wave, int lane, unsigned int tgt) {
  if (wave == 0) {
    for (;;) {
      unsigned int v = tgt;
      if (lane < 32)
        v = __hip_atomic_load(flg + lane * 16, __ATOMIC_RELAXED, __HIP_MEMORY_SCOPE_AGENT);
      if (__all((int)(v >= tgt))) break;
      __builtin_amdgcn_s_sleep(1);
    }
  }
  __syncthreads();
  __builtin_amdgcn_fence(__ATOMIC_ACQUIRE, "agent");
}

// ---------------------------------------------------------------------------
// X0 (64,1024,512) fp32 -> XX0[t][n][c] hi/lo bf16, n = d*64+b, tau = 2t+d.
// ---------------------------------------------------------------------------
__global__ void prep_x0(const float* __restrict__ X0, unsigned short* __restrict__ XH) {
  unsigned short* XL = XH + 33554432;
  __shared__ float tile[32][65];
  const int b  = blockIdx.x;        // 0..63
  const int c0 = blockIdx.y * 32;   // 0..1023 step 32
  const int tid = threadIdx.x;      // 256
  for (int tb = 0; tb < 8; ++tb) {
    const int tau0 = tb * 64;
#pragma unroll
    for (int i = 0; i < 8; ++i) {
      const int cc  = (tid >> 6) + 4 * i;
      const int tau = tid & 63;
      tile[cc][tau] = X0[(size_t)b * 524288 + (size_t)(c0 + cc) * 512 + tau0 + tau];
    }
    __syncthreads();
#pragma unroll
    for (int s = 0; s < 8; ++s) {
      const int cc  = tid & 31;
      const int tau = (tid >> 5) * 8 + s;
      const int gt  = tau0 + tau;
      const int tt  = gt >> 1, d = gt & 1;
      unsigned short h, l;
      split_bf(tile[cc][tau], h, l);
      const size_t o = (size_t)tt * 131072 + (size_t)(d * 64 + b) * 1024 + c0 + cc;
      XH[o] = h; XL[o] = l;
    }
    __syncthreads();
  }
}

// ---------------------------------------------------------------------------
// X1 (64,512,96) fp32 -> XX1[t][n][h] hi/lo bf16, t<48, tau = 2t+d.
// ---------------------------------------------------------------------------
__global__ void prep_x1(const float* __restrict__ X1, unsigned short* __restrict__ XH) {
  unsigned short* XL = XH + 3145728;
  __shared__ float tile[32][97];
  const int b  = blockIdx.x;        // 0..63
  const int h0 = blockIdx.y * 32;   // 0..511 step 32
  const int tid = threadIdx.x;
#pragma unroll
  for (int i = 0; i < 12; ++i) {
    const int idx = i * 256 + tid;  // < 3072
    const int cc = idx / 96, tau = idx % 96;
    tile[cc][tau] = X1[(size_t)b * 49152 + (size_t)(h0 + cc) * 96 + tau];
  }
  __syncthreads();
#pragma unroll
  for (int i = 0; i < 12; ++i) {
    const int idx = i * 256 + tid;
    const int cc = idx & 31, tau = idx >> 5;  // tau 0..95
    const int tt = tau >> 1, d = tau & 1;
    unsigned short h, l;
    split_bf(tile[cc][tau], h, l);
    const size_t o = (size_t)tt * 65536 + (size_t)(d * 64 + b) * 512 + h0 + cc;
    XH[o] = h; XL[o] = l;
  }
}

// ---------------------------------------------------------------------------
// Persistent recurrent kernel. Grid = 256 blocks x 256 threads (1 WG/CU).
// ---------------------------------------------------------------------------
template <bool STAGED>
__launch_bounds__(256, 1)
__global__ void rnn_persistent(unsigned char* __restrict__ ws,
                               const float* __restrict__ X0, const float* __restrict__ X1,
                               const float* __restrict__ WihE, const float* __restrict__ WhhE,
                               const float* __restrict__ bihE, const float* __restrict__ bhhE,
                               const float* __restrict__ WihD, const float* __restrict__ WhhD,
                               const float* __restrict__ bihD, const float* __restrict__ bhhD,
                               float* __restrict__ out) {
  const int tid  = threadIdx.x;
  const int wave = tid >> 6;
  const int lane = tid & 63;
  const int l15  = lane & 15;
  const int quad = lane >> 4;

  const int g  = blockIdx.x & 7;   // group (XCD-aligned under round-robin)
  const int m  = blockIdx.x >> 3;  // member 0..31
  const int rb = g * 16;           // batch-row base of group
  const int ib = m * 16;           // hidden-i base of this member

  const unsigned short* XX0H = (const unsigned short*)(ws + OFF_XX0H);
  const unsigned short* XX0L = (const unsigned short*)(ws + OFF_XX0L);
  const unsigned short* XX1H = (const unsigned short*)(ws + OFF_XX1H);
  const unsigned short* XX1L = (const unsigned short*)(ws + OFF_XX1L);
  unsigned int* HbP  = (unsigned int*)(ws + OFF_HB);   // [2][128][512] packed
  unsigned int* flg  = (unsigned int*)(ws + OFF_FLG) + (size_t)g * 512;  // 32*16 u32
  unsigned int* myfl = flg + (size_t)m * 16;

  __shared__ float red[4][6][256];  // 24 KB

  const int r_row = tid >> 4;   // batch row within group (gate phase)
  const int ii    = tid & 15;
  const int ig    = ib + ii;

  const int an    = rb + l15;               // A-operand batch row
  const int ab    = an & 63, ad = an >> 6;  // original batch / dilation
  const int onrow = rb + r_row;
  const int ob    = onrow & 63, od = onrow >> 6;

  const float bieR = bihE[ig], bieZ = bihE[512 + ig], bieN = bihE[1024 + ig];
  const float bheR = bhhE[ig], bheZ = bhhE[512 + ig], bheN = bhhE[1024 + ig];
  const float bidR = bihD[ig], bidZ = bihD[512 + ig], bidN = bihD[1024 + ig];
  const float bhdR = bhhD[ig], bhdZ = bhhD[512 + ig], bhdN = bhhD[1024 + ig];

  // ---- encoder weight fragments: fp32 -> hi/lo split in registers.
  bf16x8 WIH_H[24], WIH_L[24], WHH_H[12], WHH_L[12];
#pragma unroll
  for (int kt = 0; kt < 8; ++kt)
#pragma unroll
    for (int nt = 0; nt < 3; ++nt)
      split8(WihE + (size_t)(nt * 512 + ib + l15) * 1024 + (wave * 8 + kt) * 32 + quad * 8,
             WIH_H[kt * 3 + nt], WIH_L[kt * 3 + nt]);
#pragma unroll
  for (int kt = 0; kt < 4; ++kt)
#pragma unroll
    for (int nt = 0; nt < 3; ++nt)
      split8(WhhE + (size_t)(nt * 512 + ib + l15) * 512 + (wave * 4 + kt) * 32 + quad * 8,
             WHH_H[kt * 3 + nt], WHH_L[kt * 3 + nt]);

  // ---- init h(0) = 0 into parity-0 buffer, publish (flag value = 1)
  float h_reg = 0.0f;
  __hip_atomic_store(HbP + (size_t)onrow * 512 + ig, 0u,
                     __ATOMIC_RELAXED, __HIP_MEMORY_SCOPE_AGENT);
  __syncthreads();
  if (tid == 0) {
    __builtin_amdgcn_fence(__ATOMIC_RELEASE, "agent");
    __hip_atomic_store(myfl, 1u, __ATOMIC_RELAXED, __HIP_MEMORY_SCOPE_AGENT);
  }

  // ===================== encoder: 256 steps =====================
  for (int t = 0; t < 256; ++t) {
    const int par  = t & 1;
    const int wpar = (t + 1) & 1;

    // ---- gi = x[t] @ WihE^T  (independent of h; before the wait)
    f32x4 gi0 = {0,0,0,0}, gi1 = {0,0,0,0}, gi2 = {0,0,0,0};
    const size_t xb  = ((size_t)t * 128 + an) * 1024 + quad * 8;  // staged
    const int    tau = 2 * t + ad;                                 // direct
#pragma unroll
    for (int kt = 0; kt < 8; ++kt) {
      bf16x8 axh, axl;
      if constexpr (STAGED) {
        axh = *reinterpret_cast<const bf16x8*>(XX0H + xb + (wave * 8 + kt) * 32);
        axl = *reinterpret_cast<const bf16x8*>(XX0L + xb + (wave * 8 + kt) * 32);
      } else {
        float xv[8];
#pragma unroll
        for (int j = 0; j < 8; ++j)
          xv[j] = X0[(size_t)ab * 524288 +
                     (size_t)((wave * 8 + kt) * 32 + quad * 8 + j) * 512 + tau];
        split8a(xv, axh, axl);
      }
      gi0 = MFMA16(axh, WIH_H[kt * 3 + 0], gi0);
      gi1 = MFMA16(axh, WIH_H[kt * 3 + 1], gi1);
      gi2 = MFMA16(axh, WIH_H[kt * 3 + 2], gi2);
      gi0 = MFMA16(axl, WIH_H[kt * 3 + 0], gi0);
      gi1 = MFMA16(axl, WIH_H[kt * 3 + 1], gi1);
      gi2 = MFMA16(axl, WIH_H[kt * 3 + 2], gi2);
      gi0 = MFMA16(axh, WIH_L[kt * 3 + 0], gi0);
      gi1 = MFMA16(axh, WIH_L[kt * 3 + 1], gi1);
      gi2 = MFMA16(axh, WIH_L[kt * 3 + 2], gi2);
    }

    // ---- wait for h(t) from all group members
    wait_group(flg, wave, lane, (unsigned int)(t + 1));

    // ---- plain vectorized h loads (ordered by the acquire fence)
    const unsigned int* hrow = HbP + (size_t)par * 65536 + (size_t)an * 512 + quad * 8;
    u32x4 hv[4][2];
#pragma unroll
    for (int kt = 0; kt < 4; ++kt) {
      hv[kt][0] = *reinterpret_cast<const u32x4*>(hrow + (wave * 4 + kt) * 32);
      hv[kt][1] = *reinterpret_cast<const u32x4*>(hrow + (wave * 4 + kt) * 32 + 4);
    }
    f32x4 gh0 = {0,0,0,0}, gh1 = {0,0,0,0}, gh2 = {0,0,0,0};
#pragma unroll
    for (int kt = 0; kt < 4; ++kt) {
      bf16x8 ahh, ahl;
      union { unsigned short u; __bf16 b; } c;
#pragma unroll
      for (int j = 0; j < 8; ++j) {
        const unsigned int w = hv[kt][j >> 2][j & 3];
        c.u = (unsigned short)(w & 0xffffu); ahh[j] = c.b;
        c.u = (unsigned short)(w >> 16);     ahl[j] = c.b;
      }
      gh0 = MFMA16(ahh, WHH_H[kt * 3 + 0], gh0);
      gh1 = MFMA16(ahh, WHH_H[kt * 3 + 1], gh1);
      gh2 = MFMA16(ahh, WHH_H[kt * 3 + 2], gh2);
      gh0 = MFMA16(ahl, WHH_H[kt * 3 + 0], gh0);
      gh1 = MFMA16(ahl, WHH_H[kt * 3 + 1], gh1);
      gh2 = MFMA16(ahl, WHH_H[kt * 3 + 2], gh2);
      gh0 = MFMA16(ahh, WHH_L[kt * 3 + 0], gh0);
      gh1 = MFMA16(ahh, WHH_L[kt * 3 + 1], gh1);
      gh2 = MFMA16(ahh, WHH_L[kt * 3 + 2], gh2);
    }

    // ---- reduce 4 wave-partials (C/D layout: row=quad*4+q, col=l15)
#pragma unroll
    for (int q = 0; q < 4; ++q) {
      const int base = (quad * 4 + q) * 16 + l15;
      red[wave][0][base] = gi0[q]; red[wave][1][base] = gi1[q]; red[wave][2][base] = gi2[q];
      red[wave][3][base] = gh0[q]; red[wave][4][base] = gh1[q]; red[wave][5][base] = gh2[q];
    }
    __syncthreads();
    float sR = 0, sZ = 0, sN = 0, hR = 0, hZ = 0, hN = 0;
#pragma unroll
    for (int w = 0; w < 4; ++w) {
      sR += red[w][0][tid]; sZ += red[w][1][tid]; sN += red[w][2][tid];
      hR += red[w][3][tid]; hZ += red[w][4][tid]; hN += red[w][5][tid];
    }
    const float rr = sigmoidf_(sR + bieR + hR + bheR);
    const float zz = sigmoidf_(sZ + bieZ + hZ + bheZ);
    const float nn = tanhf_(sN + bieN + rr * (hN + bheN));
    h_reg = (1.0f - zz) * nn + zz * h_reg;
    unsigned short ph, pl;
    split_bf(h_reg, ph, pl);
    __hip_atomic_store(HbP + (size_t)wpar * 65536 + (size_t)onrow * 512 + ig,
                       (unsigned int)ph | ((unsigned int)pl << 16),
                       __ATOMIC_RELAXED, __HIP_MEMORY_SCOPE_AGENT);
    __syncthreads();  // all threads' h stores precede the release/flag
    if (tid == 0) {
      __builtin_amdgcn_fence(__ATOMIC_RELEASE, "agent");
      __hip_atomic_store(myfl, (unsigned int)(t + 2),
                         __ATOMIC_RELAXED, __HIP_MEMORY_SCOPE_AGENT);
    }
  }

  // ===================== decoder weights (fp32 -> split, reuse regs) ========
  bf16x8 D1H[12], D1L[12], D2H[12], D2L[12], DHH[12], DHL[12];
#pragma unroll
  for (int kt = 0; kt < 4; ++kt)
#pragma unroll
    for (int nt = 0; nt < 3; ++nt) {
      const size_t row = (size_t)(nt * 512 + ib + l15);
      const int    k   = (wave * 4 + kt) * 32 + quad * 8;
      split8(WihD + row * 1024 + k,       D1H[kt * 3 + nt], D1L[kt * 3 + nt]);
      split8(WihD + row * 1024 + 512 + k, D2H[kt * 3 + nt], D2L[kt * 3 + nt]);
      split8(WhhD + row * 512 + k,        DHH[kt * 3 + nt], DHL[kt * 3 + nt]);
    }

  float* orow = out + (size_t)ob * 49152 + (size_t)ig * 96 + od;

  // ===================== decoder: 48 steps (global step gt = 256 + t) =======
  for (int t = 0; t < 48; ++t) {
    const int gt   = 256 + t;
    const int par  = gt & 1;
    const int wpar = (gt + 1) & 1;

    // ---- x1 part of gi (independent of h)
    f32x4 gi0 = {0,0,0,0}, gi1 = {0,0,0,0}, gi2 = {0,0,0,0};
    const size_t x1b = ((size_t)t * 128 + an) * 512 + quad * 8;  // staged
    const int    tau = 2 * t + ad;                                // direct
#pragma unroll
    for (int kt = 0; kt < 4; ++kt) {
      bf16x8 axh, axl;
      if constexpr (STAGED) {
        axh = *reinterpret_cast<const bf16x8*>(XX1H + x1b + (wave * 4 + kt) * 32);
        axl = *reinterpret_cast<const bf16x8*>(XX1L + x1b + (wave * 4 + kt) * 32);
      } else {
        float xv[8];
#pragma unroll
        for (int j = 0; j < 8; ++j)
          xv[j] = X1[(size_t)ab * 49152 +
                     (size_t)((wave * 4 + kt) * 32 + quad * 8 + j) * 96 + tau];
        split8a(xv, axh, axl);
      }
      gi0 = MFMA16(axh, D2H[kt * 3 + 0], gi0);
      gi1 = MFMA16(axh, D2H[kt * 3 + 1], gi1);
      gi2 = MFMA16(axh, D2H[kt * 3 + 2], gi2);
      gi0 = MFMA16(axl, D2H[kt * 3 + 0], gi0);
      gi1 = MFMA16(axl, D2H[kt * 3 + 1], gi1);
      gi2 = MFMA16(axl, D2H[kt * 3 + 2], gi2);
      gi0 = MFMA16(axh, D2L[kt * 3 + 0], gi0);
      gi1 = MFMA16(axh, D2L[kt * 3 + 1], gi1);
      gi2 = MFMA16(axh, D2L[kt * 3 + 2], gi2);
    }

    wait_group(flg, wave, lane, (unsigned int)(gt + 1));

    // ---- h parts: gi += h@Wd1^T (din == h), gh = h@WhhD^T
    const unsigned int* hrow = HbP + (size_t)par * 65536 + (size_t)an * 512 + quad * 8;
    u32x4 hv[4][2];
#pragma unroll
    for (int kt = 0; kt < 4; ++kt) {
      hv[kt][0] = *reinterpret_cast<const u32x4*>(hrow + (wave * 4 + kt) * 32);
      hv[kt][1] = *reinterpret_cast<const u32x4*>(hrow + (wave * 4 + kt) * 32 + 4);
    }
    f32x4 gh0 = {0,0,0,0}, gh1 = {0,0,0,0}, gh2 = {0,0,0,0};
#pragma unroll
    for (int kt = 0; kt < 4; ++kt) {
      bf16x8 ahh, ahl;
      union { unsigned short u; __bf16 b; } c;
#pragma unroll
      for (int j = 0; j < 8; ++j) {
        const unsigned int w = hv[kt][j >> 2][j & 3];
        c.u = (unsigned short)(w & 0xffffu); ahh[j] = c.b;
        c.u = (unsigned short)(w >> 16);     ahl[j] = c.b;
      }
      gi0 = MFMA16(ahh, D1H[kt * 3 + 0], gi0);
      gi1 = MFMA16(ahh, D1H[kt * 3 + 1], gi1);
      gi2 = MFMA16(ahh, D1H[kt * 3 + 2], gi2);
      gi0 = MFMA16(ahl, D1H[kt * 3 + 0], gi0);
      gi1 = MFMA16(ahl, D1H[kt * 3 + 1], gi1);
      gi2 = MFMA16(ahl, D1H[kt * 3 + 2], gi2);
      gi0 = MFMA16(ahh, D1L[kt * 3 + 0], gi0);
      gi1 = MFMA16(ahh, D1L[kt * 3 + 1], gi1);
      gi2 = MFMA16(ahh, D1L[kt * 3 + 2], gi2);
      gh0 = MFMA16(ahh, DHH[kt * 3 + 0], gh0);
      gh1 = MFMA16(ahh, DHH[kt * 3 + 1], gh1);
      gh2 = MFMA16(ahh, DHH[kt * 3 + 2], gh2);
      gh0 = MFMA16(ahl, DHH[kt * 3 + 0], gh0);
      gh1 = MFMA16(ahl, DHH[kt * 3 + 1], gh1);
      gh2 = MFMA16(ahl, DHH[kt * 3 + 2], gh2);
      gh0 = MFMA16(ahh, DHL[kt * 3 + 0], gh0);
      gh1 = MFMA16(ahh, DHL[kt * 3 + 1], gh1);
      gh2 = MFMA16(ahh, DHL[kt * 3 + 2], gh2);
    }

#pragma unroll
    for (int q = 0; q < 4; ++q) {
      const int base = (quad * 4 + q) * 16 + l15;
      red[wave][0][base] = gi0[q]; red[wave][1][base] = gi1[q]; red[wave][2][base] = gi2[q];
      red[wave][3][base] = gh0[q]; red[wave][4][base] = gh1[q]; red[wave][5][base] = gh2[q];
    }
    __syncthreads();
    float sR = 0, sZ = 0, sN = 0, hR = 0, hZ = 0, hN = 0;
#pragma unroll
    for (int w = 0; w < 4; ++w) {
      sR += red[w][0][tid]; sZ += red[w][1][tid]; sN += red[w][2][tid];
      hR += red[w][3][tid]; hZ += red[w][4][tid]; hN += red[w][5][tid];
    }
    const float rr = sigmoidf_(sR + bidR + hR + bhdR);
    const float zz = sigmoidf_(sZ + bidZ + hZ + bhdZ);
    const float nn = tanhf_(sN + bidN + rr * (hN + bhdN));
    h_reg = (1.0f - zz) * nn + zz * h_reg;
    unsigned short ph, pl;
    split_bf(h_reg, ph, pl);
    __hip_atomic_store(HbP + (size_t)wpar * 65536 + (size_t)onrow * 512 + ig,
                       (unsigned int)ph | ((unsigned int)pl << 16),
                       __ATOMIC_RELAXED, __HIP_MEMORY_SCOPE_AGENT);
    orow[2 * t] = h_reg;  // o[b][ig][2t+d]
    __syncthreads();
    if (t < 47 && tid == 0) {
      __builtin_amdgcn_fence(__ATOMIC_RELEASE, "agent");
      __hip_atomic_store(myfl, (unsigned int)(gt + 2),
                         __ATOMIC_RELAXED, __HIP_MEMORY_SCOPE_AGENT);
    }
  }
}

extern "C" void kernel_launch(void* const* d_in, const int* in_sizes, int n_in,
                              void* d_out, int out_size, void* d_ws, size_t ws_size,
                              hipStream_t stream) {
  (void)in_sizes; (void)n_in; (void)out_size;
  const float* X0   = (const float*)d_in[0];
  const float* X1   = (const float*)d_in[1];
  // d_in[2] = seqlen (unused, fixed 512)
  const float* WihE = (const float*)d_in[3];
  const float* WhhE = (const float*)d_in[4];
  const float* bihE = (const float*)d_in[5];
  const float* bhhE = (const float*)d_in[6];
  const float* WihD = (const float*)d_in[7];
  const float* WhhD = (const float*)d_in[8];
  const float* bihD = (const float*)d_in[9];
  const float* bhhD = (const float*)d_in[10];
  unsigned char* ws = (unsigned char*)d_ws;

  const bool staged = (ws_size >= NEED_FULL);  // ws_size constant -> graph-safe

  hipMemsetAsync(ws + OFF_FLG, 0, 16384, stream);
  if (staged) {
    prep_x0<<<dim3(64, 32), 256, 0, stream>>>(X0, (unsigned short*)(ws + OFF_XX0H));
    prep_x1<<<dim3(64, 16), 256, 0, stream>>>(X1, (unsigned short*)(ws + OFF_XX1H));
    rnn_persistent<true><<<256, 256, 0, stream>>>(ws, X0, X1, WihE, WhhE, bihE, bhhE,
                                                  WihD, WhhD, bihD, bhhD, (float*)d_out);
  } else {
    rnn_persistent<false><<<256, 256, 0, stream>>>(ws, X0, X1, WihE, WhhE, bihE, bhhE,
                                                   WihD, WhhD, bihD, bhhD, (float*)d_out);
  }
}